// Round 1
// baseline (1778.882 us; speedup 1.0000x reference)
//
#include <hip/hip_runtime.h>
#include <math.h>

#define D_MODEL 1024
#define D_FF    2048
#define NE      8
#define TOPK    2
#define T_TOKENS 4096
#define TOTAL_ASSIGN (T_TOKENS * TOPK)   // 8192
#define CAP     4096                      // worst-case rows per expert
#define BM 64
#define BN 64
#define BK 16

// ---------------- ws layout (bytes) ----------------
// [0,32)      int count[8]
// [32,64)     int offset[8]
// [64,96)     int pos[8]
// [96,128)    float importance[8]
// [4096,...)  tok_expert  int[2T]        (32768 B)
// ...         tok_weight  float[2T]      (32768 B)
// ...         assign_token  int[8192+64] (33024 B)
// ...         assign_weight float[8192+64]
// ...         h float[(8192+64) * D_FF]  (~64.5 MB)
#define WS_TOKE   4096
#define WS_TOKW   (WS_TOKE + 32768)
#define WS_ATOK   (WS_TOKW + 32768)
#define WS_AWGT   (WS_ATOK + 33024)
#define WS_H      (WS_AWGT + 33024)

__device__ __forceinline__ float gelu_exact(float v) {
    return 0.5f * v * (1.0f + erff(v * 0.70710678118654752440f));
}

// ---------------- router: one wave per token ----------------
__global__ __launch_bounds__(256)
void router_kernel(const float* __restrict__ x,
                   const float* __restrict__ rw,
                   const float* __restrict__ rb,
                   int* __restrict__ count,
                   float* __restrict__ importance,
                   int* __restrict__ tok_expert,
                   float* __restrict__ tok_weight) {
    int wid  = threadIdx.x >> 6;
    int lane = threadIdx.x & 63;
    int t = blockIdx.x * 4 + wid;
    if (t >= T_TOKENS) return;

    float acc[NE];
#pragma unroll
    for (int e = 0; e < NE; e++) acc[e] = 0.f;

    const float* xrow = x + (size_t)t * D_MODEL;
#pragma unroll
    for (int i = 0; i < D_MODEL / 64; i++) {
        int d = lane + 64 * i;
        float xv = xrow[d];
#pragma unroll
        for (int e = 0; e < NE; e++) acc[e] += xv * rw[d * NE + e];
    }
#pragma unroll
    for (int off = 32; off >= 1; off >>= 1) {
#pragma unroll
        for (int e = 0; e < NE; e++) acc[e] += __shfl_down(acc[e], off);
    }

    if (lane == 0) {
        float l[NE], p[NE];
        float m = -1e30f;
#pragma unroll
        for (int e = 0; e < NE; e++) { l[e] = acc[e] + rb[e]; m = fmaxf(m, l[e]); }
        float s = 0.f;
#pragma unroll
        for (int e = 0; e < NE; e++) { p[e] = expf(l[e] - m); s += p[e]; }
        float inv = 1.f / s;
#pragma unroll
        for (int e = 0; e < NE; e++) p[e] *= inv;

        // top-2, earliest index wins ties (strict >)
        int i1 = 0; float p1 = p[0];
#pragma unroll
        for (int e = 1; e < NE; e++) if (p[e] > p1) { i1 = e; p1 = p[e]; }
        int i2 = -1; float p2 = -1.f;
#pragma unroll
        for (int e = 0; e < NE; e++) if (e != i1 && p[e] > p2) { i2 = e; p2 = p[e]; }

        float wsum = p1 + p2;
        float den = fmaxf(wsum, 1e-9f);
        float w1 = p1 / den, w2 = p2 / den;

        tok_expert[2 * t]     = i1;
        tok_expert[2 * t + 1] = i2;
        tok_weight[2 * t]     = w1;
        tok_weight[2 * t + 1] = w2;
        atomicAdd(&count[i1], 1);
        atomicAdd(&count[i2], 1);
#pragma unroll
        for (int e = 0; e < NE; e++) atomicAdd(&importance[e], p[e]);
    }
}

// ---------------- offsets (prefix over 8) ----------------
__global__ void offsets_kernel(const int* __restrict__ count,
                               int* __restrict__ offset,
                               int* __restrict__ pos) {
    if (threadIdx.x == 0) {
        int run = 0;
        for (int e = 0; e < NE; e++) { offset[e] = run; pos[e] = run; run += count[e]; }
    }
}

// ---------------- scatter assignments grouped by expert ----------------
__global__ __launch_bounds__(256)
void scatter_kernel(const int* __restrict__ tok_expert,
                    const float* __restrict__ tok_weight,
                    int* __restrict__ pos,
                    int* __restrict__ assign_token,
                    float* __restrict__ assign_weight) {
    int t = blockIdx.x * 256 + threadIdx.x;
    if (t >= T_TOKENS) return;
#pragma unroll
    for (int k = 0; k < TOPK; k++) {
        int e = tok_expert[2 * t + k];
        int slot = atomicAdd(&pos[e], 1);
        assign_token[slot]  = t;
        assign_weight[slot] = tok_weight[2 * t + k];
    }
}

// ---------------- GEMM1: h = gelu(gather(x) @ W1 + b1) ----------------
__global__ __launch_bounds__(256)
void gemm1_kernel(const float* __restrict__ x,
                  const float* __restrict__ W1,
                  const float* __restrict__ b1,
                  const int* __restrict__ count,
                  const int* __restrict__ offset,
                  const int* __restrict__ assign_token,
                  float* __restrict__ h) {
    int e = blockIdx.z;
    int M = count[e];
    int tm = blockIdx.y;
    if (tm * BM >= M) return;
    int tn = blockIdx.x;
    int off = offset[e];
    const float* Wm = W1 + (size_t)e * D_MODEL * D_FF;

    __shared__ float As[BK][BM];   // transposed: As[k][row]
    __shared__ float Bs[BK][BN];

    int tid = threadIdx.x;
    int tx = tid & 15, ty = tid >> 4;

    int ar = tid >> 2;            // row 0..63
    int ac = (tid & 3) * 4;       // k 0,4,8,12
    int arow = tm * BM + ar;
    int tokenA = 0;
    if (arow < M) tokenA = assign_token[off + arow];
    const float* aptr = x + (size_t)tokenA * D_MODEL + ac;

    int br = tid >> 4;            // k 0..15
    int bc = (tid & 15) * 4;      // col
    const float* bptr = Wm + (size_t)br * D_FF + tn * BN + bc;

    float acc[4][4] = {};
    for (int k0 = 0; k0 < D_MODEL; k0 += BK) {
        float4 av = *(const float4*)(aptr + k0);
        float4 bv = *(const float4*)(bptr + (size_t)k0 * D_FF);
        __syncthreads();
        As[ac + 0][ar] = av.x;
        As[ac + 1][ar] = av.y;
        As[ac + 2][ar] = av.z;
        As[ac + 3][ar] = av.w;
        *(float4*)&Bs[br][bc] = bv;
        __syncthreads();
#pragma unroll
        for (int k = 0; k < BK; k++) {
            float4 a = *(const float4*)&As[k][ty * 4];
            float4 b = *(const float4*)&Bs[k][tx * 4];
            acc[0][0] += a.x * b.x; acc[0][1] += a.x * b.y; acc[0][2] += a.x * b.z; acc[0][3] += a.x * b.w;
            acc[1][0] += a.y * b.x; acc[1][1] += a.y * b.y; acc[1][2] += a.y * b.z; acc[1][3] += a.y * b.w;
            acc[2][0] += a.z * b.x; acc[2][1] += a.z * b.y; acc[2][2] += a.z * b.z; acc[2][3] += a.z * b.w;
            acc[3][0] += a.w * b.x; acc[3][1] += a.w * b.y; acc[3][2] += a.w * b.z; acc[3][3] += a.w * b.w;
        }
    }

    int ncol = tn * BN + tx * 4;
    const float* b1e = b1 + (size_t)e * D_FF + ncol;
#pragma unroll
    for (int i = 0; i < 4; i++) {
        int row = tm * BM + ty * 4 + i;
        if (row < M) {
            size_t slot = (size_t)off + row;
            float4 o;
            o.x = gelu_exact(acc[i][0] + b1e[0]);
            o.y = gelu_exact(acc[i][1] + b1e[1]);
            o.z = gelu_exact(acc[i][2] + b1e[2]);
            o.w = gelu_exact(acc[i][3] + b1e[3]);
            *(float4*)&h[slot * D_FF + ncol] = o;
        }
    }
}

// ---------------- GEMM2: out += w * (h @ W2 + b2), scattered ----------------
__global__ __launch_bounds__(256)
void gemm2_kernel(const float* __restrict__ h,
                  const float* __restrict__ W2,
                  const float* __restrict__ b2,
                  const int* __restrict__ count,
                  const int* __restrict__ offset,
                  const int* __restrict__ assign_token,
                  const float* __restrict__ assign_weight,
                  float* __restrict__ out) {
    int e = blockIdx.z;
    int M = count[e];
    int tm = blockIdx.y;
    if (tm * BM >= M) return;
    int tn = blockIdx.x;
    int off = offset[e];
    const float* Wm = W2 + (size_t)e * D_FF * D_MODEL;

    __shared__ float As[BK][BM];
    __shared__ float Bs[BK][BN];

    int tid = threadIdx.x;
    int tx = tid & 15, ty = tid >> 4;

    int ar = tid >> 2;
    int ac = (tid & 3) * 4;
    // h rows are padded (+64 rows) so unguarded loads are safe
    const float* aptr = h + ((size_t)off + tm * BM + ar) * D_FF + ac;

    int br = tid >> 4;
    int bc = (tid & 15) * 4;
    const float* bptr = Wm + (size_t)br * D_MODEL + tn * BN + bc;

    float acc[4][4] = {};
    for (int k0 = 0; k0 < D_FF; k0 += BK) {
        float4 av = *(const float4*)(aptr + k0);
        float4 bv = *(const float4*)(bptr + (size_t)k0 * D_MODEL);
        __syncthreads();
        As[ac + 0][ar] = av.x;
        As[ac + 1][ar] = av.y;
        As[ac + 2][ar] = av.z;
        As[ac + 3][ar] = av.w;
        *(float4*)&Bs[br][bc] = bv;
        __syncthreads();
#pragma unroll
        for (int k = 0; k < BK; k++) {
            float4 a = *(const float4*)&As[k][ty * 4];
            float4 b = *(const float4*)&Bs[k][tx * 4];
            acc[0][0] += a.x * b.x; acc[0][1] += a.x * b.y; acc[0][2] += a.x * b.z; acc[0][3] += a.x * b.w;
            acc[1][0] += a.y * b.x; acc[1][1] += a.y * b.y; acc[1][2] += a.y * b.z; acc[1][3] += a.y * b.w;
            acc[2][0] += a.z * b.x; acc[2][1] += a.z * b.y; acc[2][2] += a.z * b.z; acc[2][3] += a.z * b.w;
            acc[3][0] += a.w * b.x; acc[3][1] += a.w * b.y; acc[3][2] += a.w * b.z; acc[3][3] += a.w * b.w;
        }
    }

    int ncol = tn * BN + tx * 4;
    const float* b2e = b2 + (size_t)e * D_MODEL + ncol;
#pragma unroll
    for (int i = 0; i < 4; i++) {
        int row = tm * BM + ty * 4 + i;
        if (row < M) {
            int t = assign_token[off + row];
            float w = assign_weight[off + row];
            float* op = out + (size_t)t * D_MODEL + ncol;
            atomicAdd(&op[0], w * (acc[i][0] + b2e[0]));
            atomicAdd(&op[1], w * (acc[i][1] + b2e[1]));
            atomicAdd(&op[2], w * (acc[i][2] + b2e[2]));
            atomicAdd(&op[3], w * (acc[i][3] + b2e[3]));
        }
    }
}

// ---------------- aux loss ----------------
__global__ void aux_kernel(const int* __restrict__ count,
                           const float* __restrict__ importance,
                           float* __restrict__ out_aux) {
    if (threadIdx.x == 0) {
        float a = 0.f;
        for (int e = 0; e < NE; e++) {
            float imp  = importance[e] / (float)T_TOKENS;
            float load = (float)count[e] / (float)TOTAL_ASSIGN;
            a += imp * load;
        }
        out_aux[0] = (float)NE * a;
    }
}

extern "C" void kernel_launch(void* const* d_in, const int* in_sizes, int n_in,
                              void* d_out, int out_size, void* d_ws, size_t ws_size,
                              hipStream_t stream) {
    const float* x  = (const float*)d_in[0];
    const float* rw = (const float*)d_in[1];
    const float* rb = (const float*)d_in[2];
    const float* W1 = (const float*)d_in[3];
    const float* b1 = (const float*)d_in[4];
    const float* W2 = (const float*)d_in[5];
    const float* b2 = (const float*)d_in[6];
    float* out = (float*)d_out;

    char* ws = (char*)d_ws;
    int*   count      = (int*)(ws + 0);
    int*   offset     = (int*)(ws + 32);
    int*   pos        = (int*)(ws + 64);
    float* importance = (float*)(ws + 96);
    int*   tok_expert = (int*)(ws + WS_TOKE);
    float* tok_weight = (float*)(ws + WS_TOKW);
    int*   assign_tok = (int*)(ws + WS_ATOK);
    float* assign_wgt = (float*)(ws + WS_AWGT);
    float* h          = (float*)(ws + WS_H);

    // zero header (counts, importance) and output (atomicAdd target)
    hipMemsetAsync(ws, 0, 4096, stream);
    hipMemsetAsync(d_out, 0, (size_t)out_size * sizeof(float), stream);

    router_kernel<<<T_TOKENS / 4, 256, 0, stream>>>(x, rw, rb, count, importance,
                                                    tok_expert, tok_weight);
    offsets_kernel<<<1, 64, 0, stream>>>(count, offset, pos);
    scatter_kernel<<<T_TOKENS / 256, 256, 0, stream>>>(tok_expert, tok_weight, pos,
                                                       assign_tok, assign_wgt);

    dim3 g1(D_FF / BN, CAP / BM, NE);
    gemm1_kernel<<<g1, 256, 0, stream>>>(x, W1, b1, count, offset, assign_tok, h);

    dim3 g2(D_MODEL / BN, CAP / BM, NE);
    gemm2_kernel<<<g2, 256, 0, stream>>>(h, W2, b2, count, offset, assign_tok,
                                         assign_wgt, out);

    aux_kernel<<<1, 64, 0, stream>>>(count, importance, out + (size_t)T_TOKENS * D_MODEL);
}

// Round 2
// 834.115 us; speedup vs baseline: 2.1327x; 2.1327x over previous
//
#include <hip/hip_runtime.h>
#include <math.h>

#define D_MODEL 1024
#define D_FF    2048
#define NE      8
#define TOPK    2
#define T_TOKENS 4096
#define TOTAL_ASSIGN (T_TOKENS * TOPK)   // 8192
#define CAP     4096                      // worst-case rows per expert
#define HROWS   (TOTAL_ASSIGN + 128)      // padded h rows

typedef __attribute__((ext_vector_type(8))) short bf16x8;
typedef __attribute__((ext_vector_type(4))) float f32x4;

// ---------------- ws layout (bytes) ----------------
#define WS_TOKE   4096                     // int[8192]
#define WS_TOKW   (WS_TOKE + 32768)        // float[8192]
#define WS_ATOK   (WS_TOKW + 32768)        // int[8320]
#define WS_AWGT   (WS_ATOK + 34816)        // float[8320]
#define WS_XBF    (WS_AWGT + 34816)        // bf16[4096*1024]      8 MB
#define WS_W1T    (WS_XBF + 8388608)       // bf16[8*2048*1024]   33.5 MB  [e][n][k]
#define WS_W2T    (WS_W1T + 33554432)      // bf16[8*1024*2048]   33.5 MB  [e][n][k]
#define WS_HBF    (WS_W2T + 33554432)      // bf16[HROWS*2048]    34.1 MB
// total ~109.7 MB

__device__ __forceinline__ float gelu_exact(float v) {
    return 0.5f * v * (1.0f + erff(v * 0.70710678118654752440f));
}

__device__ __forceinline__ short f2bf(float f) {
    union { float f; unsigned u; } v; v.f = f;
    unsigned r = v.u + 0x7FFFu + ((v.u >> 16) & 1u);   // RNE
    return (short)(r >> 16);
}

// async 16-B global->LDS (dest = wave-uniform base + lane*16)
__device__ __forceinline__ void async_copy16(void* lds, const void* g) {
    __builtin_amdgcn_global_load_lds(
        (const __attribute__((address_space(1))) unsigned int*)(uintptr_t)g,
        (__attribute__((address_space(3))) unsigned int*)(uintptr_t)lds,
        16, 0, 0);
}

// ---------------- convert x -> bf16 ----------------
__global__ __launch_bounds__(256)
void convert_x_kernel(const float* __restrict__ x, short* __restrict__ xbf) {
    int idx = (blockIdx.x * 256 + threadIdx.x) * 8;
    float4 v0 = *(const float4*)(x + idx);
    float4 v1 = *(const float4*)(x + idx + 4);
    bf16x8 o;
    o[0] = f2bf(v0.x); o[1] = f2bf(v0.y); o[2] = f2bf(v0.z); o[3] = f2bf(v0.w);
    o[4] = f2bf(v1.x); o[5] = f2bf(v1.y); o[6] = f2bf(v1.z); o[7] = f2bf(v1.w);
    *(bf16x8*)(xbf + idx) = o;
}

// ---------------- transpose + convert W[e][K][N] -> Wt[e][N][K] bf16 ----------------
__global__ __launch_bounds__(256)
void transpose_convert_kernel(const float* __restrict__ in, short* __restrict__ out,
                              int K, int N) {
    int e = blockIdx.z;
    int k0 = blockIdx.y * 64, n0 = blockIdx.x * 64;
    const float* src = in + (size_t)e * K * N;
    short* dst = out + (size_t)e * N * K;
    __shared__ float tile[64][65];
    int tid = threadIdx.x;
#pragma unroll
    for (int i = 0; i < 4; i++) {
        int lin = i * 256 + tid;
        int kk = lin >> 4;
        int nc = (lin & 15) * 4;
        float4 v = *(const float4*)(src + (size_t)(k0 + kk) * N + n0 + nc);
        tile[kk][nc + 0] = v.x; tile[kk][nc + 1] = v.y;
        tile[kk][nc + 2] = v.z; tile[kk][nc + 3] = v.w;
    }
    __syncthreads();
#pragma unroll
    for (int i = 0; i < 4; i++) {
        int lin = i * 256 + tid;
        int nn = lin >> 4;
        int kc = (lin & 15) * 4;
        short4 o;
        o.x = f2bf(tile[kc + 0][nn]);
        o.y = f2bf(tile[kc + 1][nn]);
        o.z = f2bf(tile[kc + 2][nn]);
        o.w = f2bf(tile[kc + 3][nn]);
        *(short4*)(dst + (size_t)(n0 + nn) * K + k0 + kc) = o;
    }
}

// ---------------- router: one wave per token ----------------
__global__ __launch_bounds__(256)
void router_kernel(const float* __restrict__ x,
                   const float* __restrict__ rw,
                   const float* __restrict__ rb,
                   int* __restrict__ count,
                   float* __restrict__ importance,
                   int* __restrict__ tok_expert,
                   float* __restrict__ tok_weight) {
    int wid  = threadIdx.x >> 6;
    int lane = threadIdx.x & 63;
    int t = blockIdx.x * 4 + wid;
    if (t >= T_TOKENS) return;

    float acc[NE];
#pragma unroll
    for (int e = 0; e < NE; e++) acc[e] = 0.f;

    const float* xrow = x + (size_t)t * D_MODEL;
#pragma unroll
    for (int i = 0; i < D_MODEL / 64; i++) {
        int d = lane + 64 * i;
        float xv = xrow[d];
#pragma unroll
        for (int e = 0; e < NE; e++) acc[e] += xv * rw[d * NE + e];
    }
#pragma unroll
    for (int off = 32; off >= 1; off >>= 1) {
#pragma unroll
        for (int e = 0; e < NE; e++) acc[e] += __shfl_down(acc[e], off);
    }

    if (lane == 0) {
        float l[NE], p[NE];
        float m = -1e30f;
#pragma unroll
        for (int e = 0; e < NE; e++) { l[e] = acc[e] + rb[e]; m = fmaxf(m, l[e]); }
        float s = 0.f;
#pragma unroll
        for (int e = 0; e < NE; e++) { p[e] = expf(l[e] - m); s += p[e]; }
        float inv = 1.f / s;
#pragma unroll
        for (int e = 0; e < NE; e++) p[e] *= inv;

        int i1 = 0; float p1 = p[0];
#pragma unroll
        for (int e = 1; e < NE; e++) if (p[e] > p1) { i1 = e; p1 = p[e]; }
        int i2 = -1; float p2 = -1.f;
#pragma unroll
        for (int e = 0; e < NE; e++) if (e != i1 && p[e] > p2) { i2 = e; p2 = p[e]; }

        float den = fmaxf(p1 + p2, 1e-9f);
        tok_expert[2 * t]     = i1;
        tok_expert[2 * t + 1] = i2;
        tok_weight[2 * t]     = p1 / den;
        tok_weight[2 * t + 1] = p2 / den;
        atomicAdd(&count[i1], 1);
        atomicAdd(&count[i2], 1);
#pragma unroll
        for (int e = 0; e < NE; e++) atomicAdd(&importance[e], p[e]);
    }
}

__global__ void offsets_kernel(const int* __restrict__ count,
                               int* __restrict__ offset,
                               int* __restrict__ pos) {
    if (threadIdx.x == 0) {
        int run = 0;
        for (int e = 0; e < NE; e++) { offset[e] = run; pos[e] = run; run += count[e]; }
    }
}

__global__ __launch_bounds__(256)
void scatter_kernel(const int* __restrict__ tok_expert,
                    const float* __restrict__ tok_weight,
                    int* __restrict__ pos,
                    int* __restrict__ assign_token,
                    float* __restrict__ assign_weight) {
    int t = blockIdx.x * 256 + threadIdx.x;
    if (t >= T_TOKENS) return;
#pragma unroll
    for (int k = 0; k < TOPK; k++) {
        int e = tok_expert[2 * t + k];
        int slot = atomicAdd(&pos[e], 1);
        assign_token[slot]  = t;
        assign_weight[slot] = tok_weight[2 * t + k];
    }
}

// ---------------- MFMA grouped GEMM ----------------
// C[128x128] per block, 4 waves in 2x2, each wave 4x4 16x16 tiles, BK=32.
// A: rows gathered (GATHER) from xbf[token][K] or contiguous hbf[(off+row)][K]
// B: Wt[e][n][k]  (k-contiguous)
template<int KDIM, int NDIM, bool GATHER>
__global__ __launch_bounds__(256)
void moe_gemm_kernel(const short* __restrict__ Abase,
                     const short* __restrict__ Wt,
                     const float* __restrict__ bias,
                     const int* __restrict__ count,
                     const int* __restrict__ offset,
                     const int* __restrict__ assign_token,
                     const float* __restrict__ assign_weight,
                     short* __restrict__ hout,
                     float* __restrict__ out) {
    int e = blockIdx.z;
    int M = count[e];
    int tm = blockIdx.y;
    if (tm * 128 >= M) return;
    int tn = blockIdx.x;
    int off = offset[e];

    __shared__ __align__(16) short As[128 * 32];
    __shared__ __align__(16) short Bs[128 * 32];

    int tid = threadIdx.x;

    // staging source pointers (constant row/col per thread across K-loop)
    const short* gA[2];
    const short* gB[2];
#pragma unroll
    for (int i = 0; i < 2; i++) {
        int f = i * 256 + tid;
        int rc = f >> 2;            // row (A) / n (B), 0..127
        int kc = (f & 3) * 8;       // k-chunk start
        int r = tm * 128 + rc;
        if (GATHER) {
            int tok = (r < M) ? assign_token[off + r] : 0;
            gA[i] = Abase + (size_t)tok * KDIM + kc;
        } else {
            gA[i] = Abase + ((size_t)(off + r)) * KDIM + kc;   // hbf padded rows: safe
        }
        gB[i] = Wt + ((size_t)e * NDIM + tn * 128 + rc) * KDIM + kc;
    }

    int lane = tid & 63;
    int wid  = tid >> 6;
    int rowbase = (wid >> 1) * 64;
    int colbase = (wid & 1) * 64;
    int mrow = lane & 15;
    int quad = lane >> 4;

    f32x4 acc[4][4];
#pragma unroll
    for (int i = 0; i < 4; i++)
#pragma unroll
        for (int j = 0; j < 4; j++) acc[i][j] = (f32x4){0.f, 0.f, 0.f, 0.f};

    const short* a0 = As + (rowbase + mrow) * 32 + quad * 8;
    const short* b0 = Bs + (colbase + mrow) * 32 + quad * 8;
    short* ldsA0 = As + tid * 8;
    short* ldsA1 = As + (256 + tid) * 8;
    short* ldsB0 = Bs + tid * 8;
    short* ldsB1 = Bs + (256 + tid) * 8;

    for (int k0 = 0; k0 < KDIM; k0 += 32) {
        __syncthreads();
        async_copy16(ldsA0, gA[0] + k0);
        async_copy16(ldsA1, gA[1] + k0);
        async_copy16(ldsB0, gB[0] + k0);
        async_copy16(ldsB1, gB[1] + k0);
        __syncthreads();   // drains vmcnt (global_load_lds) before LDS reads

        bf16x8 a[4], b[4];
#pragma unroll
        for (int i = 0; i < 4; i++) a[i] = *(const bf16x8*)(a0 + i * 16 * 32);
#pragma unroll
        for (int j = 0; j < 4; j++) b[j] = *(const bf16x8*)(b0 + j * 16 * 32);
#pragma unroll
        for (int i = 0; i < 4; i++)
#pragma unroll
            for (int j = 0; j < 4; j++)
                acc[i][j] = __builtin_amdgcn_mfma_f32_16x16x32_bf16(a[i], b[j], acc[i][j], 0, 0, 0);
    }

    // epilogue: D row = quad*4 + reg (m), col = lane&15 (n)
    const float* be = bias + (size_t)e * NDIM;
    if (GATHER) {
        // h = gelu(acc + b1) -> bf16
#pragma unroll
        for (int i = 0; i < 4; i++) {
#pragma unroll
            for (int r = 0; r < 4; r++) {
                int row = tm * 128 + rowbase + i * 16 + quad * 4 + r;
                if (row < M) {
                    size_t hrow = (size_t)(off + row) * NDIM;
#pragma unroll
                    for (int j = 0; j < 4; j++) {
                        int col = tn * 128 + colbase + j * 16 + mrow;
                        float v = acc[i][j][r] + be[col];
                        hout[hrow + col] = f2bf(gelu_exact(v));
                    }
                }
            }
        }
    } else {
        // out[token] += w * (acc + b2)
#pragma unroll
        for (int i = 0; i < 4; i++) {
#pragma unroll
            for (int r = 0; r < 4; r++) {
                int row = tm * 128 + rowbase + i * 16 + quad * 4 + r;
                if (row < M) {
                    int t = assign_token[off + row];
                    float w = assign_weight[off + row];
                    float* op = out + (size_t)t * NDIM;
#pragma unroll
                    for (int j = 0; j < 4; j++) {
                        int col = tn * 128 + colbase + j * 16 + mrow;
                        atomicAdd(&op[col], w * (acc[i][j][r] + be[col]));
                    }
                }
            }
        }
    }
}

__global__ void aux_kernel(const int* __restrict__ count,
                           const float* __restrict__ importance,
                           float* __restrict__ out_aux) {
    if (threadIdx.x == 0) {
        float a = 0.f;
        for (int e = 0; e < NE; e++) {
            float imp  = importance[e] / (float)T_TOKENS;
            float load = (float)count[e] / (float)TOTAL_ASSIGN;
            a += imp * load;
        }
        out_aux[0] = (float)NE * a;
    }
}

extern "C" void kernel_launch(void* const* d_in, const int* in_sizes, int n_in,
                              void* d_out, int out_size, void* d_ws, size_t ws_size,
                              hipStream_t stream) {
    const float* x  = (const float*)d_in[0];
    const float* rw = (const float*)d_in[1];
    const float* rb = (const float*)d_in[2];
    const float* W1 = (const float*)d_in[3];
    const float* b1 = (const float*)d_in[4];
    const float* W2 = (const float*)d_in[5];
    const float* b2 = (const float*)d_in[6];
    float* out = (float*)d_out;

    char* ws = (char*)d_ws;
    int*   count      = (int*)(ws + 0);
    int*   offset     = (int*)(ws + 32);
    int*   pos        = (int*)(ws + 64);
    float* importance = (float*)(ws + 96);
    int*   tok_expert = (int*)(ws + WS_TOKE);
    float* tok_weight = (float*)(ws + WS_TOKW);
    int*   assign_tok = (int*)(ws + WS_ATOK);
    float* assign_wgt = (float*)(ws + WS_AWGT);
    short* xbf        = (short*)(ws + WS_XBF);
    short* W1t        = (short*)(ws + WS_W1T);
    short* W2t        = (short*)(ws + WS_W2T);
    short* hbf        = (short*)(ws + WS_HBF);

    hipMemsetAsync(ws, 0, 4096, stream);
    hipMemsetAsync(d_out, 0, (size_t)out_size * sizeof(float), stream);

    // conversions (independent of router)
    convert_x_kernel<<<T_TOKENS * D_MODEL / (256 * 8), 256, 0, stream>>>(x, xbf);
    {
        dim3 g(D_FF / 64, D_MODEL / 64, NE);     // W1: K=1024, N=2048
        transpose_convert_kernel<<<g, 256, 0, stream>>>(W1, W1t, D_MODEL, D_FF);
    }
    {
        dim3 g(D_MODEL / 64, D_FF / 64, NE);     // W2: K=2048, N=1024
        transpose_convert_kernel<<<g, 256, 0, stream>>>(W2, W2t, D_FF, D_MODEL);
    }

    router_kernel<<<T_TOKENS / 4, 256, 0, stream>>>(x, rw, rb, count, importance,
                                                    tok_expert, tok_weight);
    offsets_kernel<<<1, 64, 0, stream>>>(count, offset, pos);
    scatter_kernel<<<T_TOKENS / 256, 256, 0, stream>>>(tok_expert, tok_weight, pos,
                                                       assign_tok, assign_wgt);

    {
        dim3 g(D_FF / 128, CAP / 128, NE);       // gemm1: K=1024, N=2048
        moe_gemm_kernel<D_MODEL, D_FF, true><<<g, 256, 0, stream>>>(
            xbf, W1t, b1, count, offset, assign_tok, assign_wgt, hbf, nullptr);
    }
    {
        dim3 g(D_MODEL / 128, CAP / 128, NE);    // gemm2: K=2048, N=1024
        moe_gemm_kernel<D_FF, D_MODEL, false><<<g, 256, 0, stream>>>(
            hbf, W2t, b2, count, offset, assign_tok, assign_wgt, nullptr, out);
    }

    aux_kernel<<<1, 64, 0, stream>>>(count, importance, out + (size_t)T_TOKENS * D_MODEL);
}

// Round 3
// 358.274 us; speedup vs baseline: 4.9652x; 2.3282x over previous
//
#include <hip/hip_runtime.h>
#include <math.h>

#define D_MODEL 1024
#define D_FF    2048
#define NE      8
#define TOPK    2
#define T_TOKENS 4096
#define TOTAL_ASSIGN (T_TOKENS * TOPK)   // 8192
#define CAP     4096                      // worst-case rows per expert
#define HROWS   (TOTAL_ASSIGN + 128)      // padded assignment rows

typedef __attribute__((ext_vector_type(8))) short bf16x8;
typedef __attribute__((ext_vector_type(4))) float f32x4;

// ---------------- ws layout (bytes) ----------------
#define WS_TOKE   4096                     // int[8192] tok_expert
#define WS_TOKW   (WS_TOKE + 32768)        // float[8192] tok_weight (renormalized top-2)
#define WS_ATOK   (WS_TOKW + 32768)        // int[HROWS] assign_token
#define WS_AWGT   (WS_ATOK + 34816)        // float[HROWS] assign_weight
#define WS_XBF    (WS_AWGT + 34816)        // bf16[4096*1024]      8 MB
#define WS_W1T    (WS_XBF + 8388608)       // bf16[8*2048*1024]   33.5 MB  [e][n][k]
#define WS_W2T    (WS_W1T + 33554432)      // bf16[8*1024*2048]   33.5 MB  [e][n][k]
#define WS_HBF    (WS_W2T + 33554432)      // bf16[HROWS*2048]    34.1 MB
#define WS_PROBS  (WS_HBF + 34078720)      // float[4096*8] softmax probs  128 KB
#define WS_INV    (WS_PROBS + 131072)      // int[8192] token,k -> slot
#define WS_Y      (WS_INV + 32768)         // float[HROWS*1024]  expert outputs 34.1 MB
#define WS_END    (WS_Y + 34078720)        // ~144 MB

__device__ __forceinline__ float gelu_exact(float v) {
    return 0.5f * v * (1.0f + erff(v * 0.70710678118654752440f));
}

__device__ __forceinline__ short f2bf(float f) {
    union { float f; unsigned u; } v; v.f = f;
    unsigned r = v.u + 0x7FFFu + ((v.u >> 16) & 1u);   // RNE
    return (short)(r >> 16);
}

// async 16-B global->LDS (dest = wave-uniform base + lane*16)
__device__ __forceinline__ void async_copy16(void* lds, const void* g) {
    __builtin_amdgcn_global_load_lds(
        (const __attribute__((address_space(1))) unsigned int*)(uintptr_t)g,
        (__attribute__((address_space(3))) unsigned int*)(uintptr_t)lds,
        16, 0, 0);
}

// ---------------- convert x -> bf16 ----------------
__global__ __launch_bounds__(256)
void convert_x_kernel(const float* __restrict__ x, short* __restrict__ xbf) {
    int idx = (blockIdx.x * 256 + threadIdx.x) * 8;
    float4 v0 = *(const float4*)(x + idx);
    float4 v1 = *(const float4*)(x + idx + 4);
    bf16x8 o;
    o[0] = f2bf(v0.x); o[1] = f2bf(v0.y); o[2] = f2bf(v0.z); o[3] = f2bf(v0.w);
    o[4] = f2bf(v1.x); o[5] = f2bf(v1.y); o[6] = f2bf(v1.z); o[7] = f2bf(v1.w);
    *(bf16x8*)(xbf + idx) = o;
}

// ---------------- transpose + convert W[e][K][N] -> Wt[e][N][K] bf16 ----------------
__global__ __launch_bounds__(256)
void transpose_convert_kernel(const float* __restrict__ in, short* __restrict__ out,
                              int K, int N) {
    int e = blockIdx.z;
    int k0 = blockIdx.y * 64, n0 = blockIdx.x * 64;
    const float* src = in + (size_t)e * K * N;
    short* dst = out + (size_t)e * N * K;
    __shared__ float tile[64][65];
    int tid = threadIdx.x;
#pragma unroll
    for (int i = 0; i < 4; i++) {
        int lin = i * 256 + tid;
        int kk = lin >> 4;
        int nc = (lin & 15) * 4;
        float4 v = *(const float4*)(src + (size_t)(k0 + kk) * N + n0 + nc);
        tile[kk][nc + 0] = v.x; tile[kk][nc + 1] = v.y;
        tile[kk][nc + 2] = v.z; tile[kk][nc + 3] = v.w;
    }
    __syncthreads();
#pragma unroll
    for (int i = 0; i < 4; i++) {
        int lin = i * 256 + tid;
        int nn = lin >> 4;
        int kc = (lin & 15) * 4;
        short4 o;
        o.x = f2bf(tile[kc + 0][nn]);
        o.y = f2bf(tile[kc + 1][nn]);
        o.z = f2bf(tile[kc + 2][nn]);
        o.w = f2bf(tile[kc + 3][nn]);
        *(short4*)(dst + (size_t)(n0 + nn) * K + k0 + kc) = o;
    }
}

// ---------------- router: one wave per token, NO atomics ----------------
__global__ __launch_bounds__(256)
void router_kernel(const float* __restrict__ x,
                   const float* __restrict__ rw,
                   const float* __restrict__ rb,
                   float* __restrict__ probs,
                   int* __restrict__ tok_expert,
                   float* __restrict__ tok_weight) {
    int wid  = threadIdx.x >> 6;
    int lane = threadIdx.x & 63;
    int t = blockIdx.x * 4 + wid;
    if (t >= T_TOKENS) return;

    float acc[NE];
#pragma unroll
    for (int e = 0; e < NE; e++) acc[e] = 0.f;

    const float* xrow = x + (size_t)t * D_MODEL;
#pragma unroll
    for (int i = 0; i < D_MODEL / 64; i++) {
        int d = lane + 64 * i;
        float xv = xrow[d];
#pragma unroll
        for (int e = 0; e < NE; e++) acc[e] += xv * rw[d * NE + e];
    }
#pragma unroll
    for (int off = 32; off >= 1; off >>= 1) {
#pragma unroll
        for (int e = 0; e < NE; e++) acc[e] += __shfl_down(acc[e], off);
    }

    if (lane == 0) {
        float l[NE], p[NE];
        float m = -1e30f;
#pragma unroll
        for (int e = 0; e < NE; e++) { l[e] = acc[e] + rb[e]; m = fmaxf(m, l[e]); }
        float s = 0.f;
#pragma unroll
        for (int e = 0; e < NE; e++) { p[e] = expf(l[e] - m); s += p[e]; }
        float inv = 1.f / s;
#pragma unroll
        for (int e = 0; e < NE; e++) p[e] *= inv;

        *(float4*)&probs[t * NE]     = make_float4(p[0], p[1], p[2], p[3]);
        *(float4*)&probs[t * NE + 4] = make_float4(p[4], p[5], p[6], p[7]);

        int i1 = 0; float p1 = p[0];
#pragma unroll
        for (int e = 1; e < NE; e++) if (p[e] > p1) { i1 = e; p1 = p[e]; }
        int i2 = -1; float p2 = -1.f;
#pragma unroll
        for (int e = 0; e < NE; e++) if (e != i1 && p[e] > p2) { i2 = e; p2 = p[e]; }

        float den = fmaxf(p1 + p2, 1e-9f);
        tok_expert[2 * t]     = i1;
        tok_expert[2 * t + 1] = i2;
        tok_weight[2 * t]     = p1 / den;
        tok_weight[2 * t + 1] = p2 / den;
    }
}

// ---------------- reduce: counts, offsets, importance, aux (1 block) ----------------
__global__ __launch_bounds__(256)
void reduce_kernel(const int* __restrict__ tok_expert,
                   const float* __restrict__ probs,
                   int* __restrict__ count,
                   int* __restrict__ offset,
                   int* __restrict__ pos,
                   float* __restrict__ out_aux) {
    __shared__ int   s_cnt[NE];
    __shared__ float s_imp[NE];
    int tid = threadIdx.x;
    if (tid < NE) { s_cnt[tid] = 0; s_imp[tid] = 0.f; }
    __syncthreads();

    int   cnt[NE];
    float imp[NE];
#pragma unroll
    for (int k = 0; k < NE; k++) { cnt[k] = 0; imp[k] = 0.f; }

    // counts over 8192 assignments
    for (int j = 0; j < TOTAL_ASSIGN / 256; j++) {
        int e = tok_expert[tid + 256 * j];
#pragma unroll
        for (int k = 0; k < NE; k++) cnt[k] += (e == k) ? 1 : 0;
    }
    // importance over 4096 rows of probs
    for (int j = 0; j < T_TOKENS / 256; j++) {
        const float* pr = probs + (size_t)(tid + 256 * j) * NE;
        float4 a = *(const float4*)pr;
        float4 b = *(const float4*)(pr + 4);
        imp[0] += a.x; imp[1] += a.y; imp[2] += a.z; imp[3] += a.w;
        imp[4] += b.x; imp[5] += b.y; imp[6] += b.z; imp[7] += b.w;
    }

#pragma unroll
    for (int off = 32; off >= 1; off >>= 1) {
#pragma unroll
        for (int k = 0; k < NE; k++) {
            cnt[k] += __shfl_down(cnt[k], off);
            imp[k] += __shfl_down(imp[k], off);
        }
    }
    if ((tid & 63) == 0) {
#pragma unroll
        for (int k = 0; k < NE; k++) {
            atomicAdd(&s_cnt[k], cnt[k]);
            atomicAdd(&s_imp[k], imp[k]);
        }
    }
    __syncthreads();
    if (tid == 0) {
        int run = 0;
        float a = 0.f;
        for (int e = 0; e < NE; e++) {
            int c = s_cnt[e];
            count[e] = c; offset[e] = run; pos[e] = run; run += c;
            a += (s_imp[e] / (float)T_TOKENS) * ((float)c / (float)TOTAL_ASSIGN);
        }
        out_aux[0] = (float)NE * a;
    }
}

// ---------------- hierarchical scatter: 128 global atomics total ----------------
__global__ __launch_bounds__(256)
void scatter_kernel(const int* __restrict__ tok_expert,
                    const float* __restrict__ tok_weight,
                    int* __restrict__ pos,
                    int* __restrict__ assign_token,
                    float* __restrict__ assign_weight,
                    int* __restrict__ inv_slot) {
    __shared__ int lcnt[NE];
    __shared__ int lbase[NE];
    int tid = threadIdx.x;
    int t = blockIdx.x * 256 + tid;
    if (tid < NE) lcnt[tid] = 0;
    __syncthreads();

    int e[TOPK], lslot[TOPK];
#pragma unroll
    for (int k = 0; k < TOPK; k++) {
        e[k] = tok_expert[2 * t + k];
        lslot[k] = atomicAdd(&lcnt[e[k]], 1);
    }
    __syncthreads();
    if (tid < NE) lbase[tid] = atomicAdd(&pos[tid], lcnt[tid]);
    __syncthreads();
#pragma unroll
    for (int k = 0; k < TOPK; k++) {
        int slot = lbase[e[k]] + lslot[k];
        assign_token[slot]  = t;
        assign_weight[slot] = tok_weight[2 * t + k];
        inv_slot[2 * t + k] = slot;
    }
}

// ---------------- MFMA grouped GEMM ----------------
// MODE 0: gemm1 (gather x rows, gelu -> hout bf16)
// MODE 1: gemm2, plain stores of y[slot] = acc + bias (fp32)
// MODE 2: gemm2, atomicAdd into out (fallback)
template<int KDIM, int NDIM, int MODE>
__global__ __launch_bounds__(256)
void moe_gemm_kernel(const short* __restrict__ Abase,
                     const short* __restrict__ Wt,
                     const float* __restrict__ bias,
                     const int* __restrict__ count,
                     const int* __restrict__ offset,
                     const int* __restrict__ assign_token,
                     const float* __restrict__ assign_weight,
                     short* __restrict__ hout,
                     float* __restrict__ yout,
                     float* __restrict__ out) {
    int e = blockIdx.z;
    int M = count[e];
    int tm = blockIdx.y;
    if (tm * 128 >= M) return;
    int tn = blockIdx.x;
    int off = offset[e];

    __shared__ __align__(16) short As[128 * 32];
    __shared__ __align__(16) short Bs[128 * 32];

    int tid = threadIdx.x;

    const short* gA[2];
    const short* gB[2];
#pragma unroll
    for (int i = 0; i < 2; i++) {
        int f = i * 256 + tid;
        int rc = f >> 2;            // row (A) / n (B), 0..127
        int kc = (f & 3) * 8;       // k-chunk start
        int r = tm * 128 + rc;
        if (MODE == 0) {
            int tok = (r < M) ? assign_token[off + r] : 0;
            gA[i] = Abase + (size_t)tok * KDIM + kc;
        } else {
            gA[i] = Abase + ((size_t)(off + r)) * KDIM + kc;   // padded rows: safe
        }
        gB[i] = Wt + ((size_t)e * NDIM + tn * 128 + rc) * KDIM + kc;
    }

    int lane = tid & 63;
    int wid  = tid >> 6;
    int rowbase = (wid >> 1) * 64;
    int colbase = (wid & 1) * 64;
    int mrow = lane & 15;
    int quad = lane >> 4;

    f32x4 acc[4][4];
#pragma unroll
    for (int i = 0; i < 4; i++)
#pragma unroll
        for (int j = 0; j < 4; j++) acc[i][j] = (f32x4){0.f, 0.f, 0.f, 0.f};

    const short* a0 = As + (rowbase + mrow) * 32 + quad * 8;
    const short* b0 = Bs + (colbase + mrow) * 32 + quad * 8;
    short* ldsA0 = As + tid * 8;
    short* ldsA1 = As + (256 + tid) * 8;
    short* ldsB0 = Bs + tid * 8;
    short* ldsB1 = Bs + (256 + tid) * 8;

    for (int k0 = 0; k0 < KDIM; k0 += 32) {
        __syncthreads();
        async_copy16(ldsA0, gA[0] + k0);
        async_copy16(ldsA1, gA[1] + k0);
        async_copy16(ldsB0, gB[0] + k0);
        async_copy16(ldsB1, gB[1] + k0);
        __syncthreads();

        bf16x8 a[4], b[4];
#pragma unroll
        for (int i = 0; i < 4; i++) a[i] = *(const bf16x8*)(a0 + i * 16 * 32);
#pragma unroll
        for (int j = 0; j < 4; j++) b[j] = *(const bf16x8*)(b0 + j * 16 * 32);
#pragma unroll
        for (int i = 0; i < 4; i++)
#pragma unroll
            for (int j = 0; j < 4; j++)
                acc[i][j] = __builtin_amdgcn_mfma_f32_16x16x32_bf16(a[i], b[j], acc[i][j], 0, 0, 0);
    }

    // epilogue: D row = quad*4 + reg (m), col = lane&15 (n)
    const float* be = bias + (size_t)e * NDIM;
#pragma unroll
    for (int i = 0; i < 4; i++) {
#pragma unroll
        for (int r = 0; r < 4; r++) {
            int row = tm * 128 + rowbase + i * 16 + quad * 4 + r;
            if (row < M) {
                if (MODE == 0) {
                    size_t hrow = (size_t)(off + row) * NDIM;
#pragma unroll
                    for (int j = 0; j < 4; j++) {
                        int col = tn * 128 + colbase + j * 16 + mrow;
                        hout[hrow + col] = f2bf(gelu_exact(acc[i][j][r] + be[col]));
                    }
                } else if (MODE == 1) {
                    float* yp = yout + (size_t)(off + row) * NDIM;
#pragma unroll
                    for (int j = 0; j < 4; j++) {
                        int col = tn * 128 + colbase + j * 16 + mrow;
                        yp[col] = acc[i][j][r] + be[col];
                    }
                } else {
                    int t = assign_token[off + row];
                    float w = assign_weight[off + row];
                    float* op = out + (size_t)t * NDIM;
#pragma unroll
                    for (int j = 0; j < 4; j++) {
                        int col = tn * 128 + colbase + j * 16 + mrow;
                        atomicAdd(&op[col], w * (acc[i][j][r] + be[col]));
                    }
                }
            }
        }
    }
}

// ---------------- combine: out[t] = w1*y[s1] + w2*y[s2] (one block per token) ----------------
__global__ __launch_bounds__(256)
void combine_kernel(const float* __restrict__ y,
                    const int* __restrict__ inv_slot,
                    const float* __restrict__ tok_weight,
                    float* __restrict__ out) {
    int t = blockIdx.x;
    int c = threadIdx.x * 4;
    int s1 = inv_slot[2 * t], s2 = inv_slot[2 * t + 1];
    float w1 = tok_weight[2 * t], w2 = tok_weight[2 * t + 1];
    float4 a = *(const float4*)(y + (size_t)s1 * D_MODEL + c);
    float4 b = *(const float4*)(y + (size_t)s2 * D_MODEL + c);
    float4 o;
    o.x = w1 * a.x + w2 * b.x;
    o.y = w1 * a.y + w2 * b.y;
    o.z = w1 * a.z + w2 * b.z;
    o.w = w1 * a.w + w2 * b.w;
    *(float4*)(out + (size_t)t * D_MODEL + c) = o;
}

extern "C" void kernel_launch(void* const* d_in, const int* in_sizes, int n_in,
                              void* d_out, int out_size, void* d_ws, size_t ws_size,
                              hipStream_t stream) {
    const float* x  = (const float*)d_in[0];
    const float* rw = (const float*)d_in[1];
    const float* rb = (const float*)d_in[2];
    const float* W1 = (const float*)d_in[3];
    const float* b1 = (const float*)d_in[4];
    const float* W2 = (const float*)d_in[5];
    const float* b2 = (const float*)d_in[6];
    float* out = (float*)d_out;

    char* ws = (char*)d_ws;
    int*   count      = (int*)(ws + 0);
    int*   offset     = (int*)(ws + 32);
    int*   pos        = (int*)(ws + 64);
    int*   tok_expert = (int*)(ws + WS_TOKE);
    float* tok_weight = (float*)(ws + WS_TOKW);
    int*   assign_tok = (int*)(ws + WS_ATOK);
    float* assign_wgt = (float*)(ws + WS_AWGT);
    short* xbf        = (short*)(ws + WS_XBF);
    short* W1t        = (short*)(ws + WS_W1T);
    short* W2t        = (short*)(ws + WS_W2T);
    short* hbf        = (short*)(ws + WS_HBF);
    float* probs      = (float*)(ws + WS_PROBS);
    int*   inv_slot   = (int*)(ws + WS_INV);
    float* y          = (float*)(ws + WS_Y);

    bool fits = ws_size >= (size_t)WS_END;

    // conversions (independent of router)
    convert_x_kernel<<<T_TOKENS * D_MODEL / (256 * 8), 256, 0, stream>>>(x, xbf);
    {
        dim3 g(D_FF / 64, D_MODEL / 64, NE);     // W1: K=1024, N=2048
        transpose_convert_kernel<<<g, 256, 0, stream>>>(W1, W1t, D_MODEL, D_FF);
    }
    {
        dim3 g(D_MODEL / 64, D_FF / 64, NE);     // W2: K=2048, N=1024
        transpose_convert_kernel<<<g, 256, 0, stream>>>(W2, W2t, D_FF, D_MODEL);
    }

    router_kernel<<<T_TOKENS / 4, 256, 0, stream>>>(x, rw, rb, probs,
                                                    tok_expert, tok_weight);
    reduce_kernel<<<1, 256, 0, stream>>>(tok_expert, probs, count, offset, pos,
                                         out + (size_t)T_TOKENS * D_MODEL);
    scatter_kernel<<<T_TOKENS / 256, 256, 0, stream>>>(tok_expert, tok_weight, pos,
                                                       assign_tok, assign_wgt, inv_slot);

    {
        dim3 g(D_FF / 128, CAP / 128, NE);       // gemm1: K=1024, N=2048
        moe_gemm_kernel<D_MODEL, D_FF, 0><<<g, 256, 0, stream>>>(
            xbf, W1t, b1, count, offset, assign_tok, assign_wgt, hbf, nullptr, nullptr);
    }

    if (fits) {
        dim3 g(D_MODEL / 128, CAP / 128, NE);    // gemm2: K=2048, N=1024
        moe_gemm_kernel<D_FF, D_MODEL, 1><<<g, 256, 0, stream>>>(
            hbf, W2t, b2, count, offset, assign_tok, assign_wgt, nullptr, y, nullptr);
        combine_kernel<<<T_TOKENS, 256, 0, stream>>>(y, inv_slot, tok_weight, out);
    } else {
        hipMemsetAsync(d_out, 0, (size_t)T_TOKENS * D_MODEL * sizeof(float), stream);
        dim3 g(D_MODEL / 128, CAP / 128, NE);
        moe_gemm_kernel<D_FF, D_MODEL, 2><<<g, 256, 0, stream>>>(
            hbf, W2t, b2, count, offset, assign_tok, assign_wgt, nullptr, nullptr, out);
    }
}